// Round 6
// baseline (990.940 us; speedup 1.0000x reference)
//
#include <hip/hip_runtime.h>
#include <hip/hip_bf16.h>
#include <math.h>

#define N_NODES 100000
#define N_EDGES 3200000
#define NBUK 782      // ceil(100000 / 128), bucket = dst >> 7
#define BCAP 4800     // per-bucket LDS capacity (mean 4096, sigma ~64)
#define EPB 12500     // edges per staged-scatter block (256 blocks exactly)

typedef __hip_bfloat16 bf16_t;
typedef __attribute__((ext_vector_type(8))) short bf16x8;
typedef __attribute__((ext_vector_type(4))) float floatx4;
typedef __attribute__((ext_vector_type(2))) float f32x2;

// ---------- bf16 helpers (manual, branch-free) ----------
__device__ inline float2 bf2_to_f2(unsigned u) {
  float2 f;
  f.x = __uint_as_float(u << 16);
  f.y = __uint_as_float(u & 0xffff0000u);
  return f;
}
__device__ inline unsigned f2_to_bf2(float x, float y) {
  unsigned ux = __float_as_uint(x);
  unsigned uy = __float_as_uint(y);
  unsigned bx = (ux + 0x7fffu + ((ux >> 16) & 1u)) >> 16;
  unsigned by = (uy + 0x7fffu + ((uy >> 16) & 1u)) & 0xffff0000u;
  return bx | by;
}
__device__ inline unsigned f_to_bf1(float x) {
  unsigned u = __float_as_uint(x);
  return (u + 0x7fffu + ((u >> 16) & 1u)) >> 16;
}
__device__ inline unsigned relu_bf2(unsigned u) {
  unsigned lo = (u & 0x8000u) ? 0u : (u & 0xFFFFu);
  unsigned hi = (u & 0x80000000u) ? 0u : (u & 0xFFFF0000u);
  return lo | hi;
}

// ---------------------------------------------------------------------------
// CSR build, bucketed two-pass with block-staged scatter (R4: WRITE_SIZE
// 180 MB -> full-line writebacks; scatter off the critical top-5).
// ---------------------------------------------------------------------------
__global__ __launch_bounds__(256) void bucket_hist_kernel(
    const int* __restrict__ edst, int* __restrict__ cntp) {
  __shared__ int h[NBUK];
  for (int i = threadIdx.x; i < NBUK; i += 256) h[i] = 0;
  __syncthreads();
  int start = blockIdx.x * 4096;
  int end = start + 4096 < N_EDGES ? start + 4096 : N_EDGES;
  for (int i = start + threadIdx.x; i < end; i += 256)
    atomicAdd(&h[edst[i] >> 7], 1);
  __syncthreads();
  for (int i = threadIdx.x; i < NBUK; i += 256)
    if (h[i]) atomicAdd(&cntp[i << 4], h[i]);
}

__global__ __launch_bounds__(1024) void scan_buckets_kernel(
    const int* __restrict__ cntp, int* __restrict__ base,
    int* __restrict__ cursorp, int* __restrict__ rowptr) {
  __shared__ int sc[1024];
  int t = threadIdx.x;
  int v = (t < NBUK) ? cntp[t << 4] : 0;
  sc[t] = v;
  __syncthreads();
  #pragma unroll
  for (int off = 1; off < 1024; off <<= 1) {
    int u = (t >= off) ? sc[t - off] : 0;
    __syncthreads();
    sc[t] += u;
    __syncthreads();
  }
  int ex = sc[t] - v;  // exclusive
  if (t < NBUK) { base[t] = ex; cursorp[t << 4] = ex; }
  if (t == NBUK - 1) base[NBUK] = ex + v;
  if (t == 0) rowptr[N_NODES] = N_EDGES;
}

__global__ __launch_bounds__(256) void staged_scatter_kernel(
    const int* __restrict__ esrc, const int* __restrict__ edst,
    const float* __restrict__ eval, int* __restrict__ cursorp,
    int2* __restrict__ tmp) {
  __shared__ int h[NBUK];   // local hist, then local cursor
  __shared__ int gb[NBUK];  // reserved global base per bucket
  const int tid = threadIdx.x;
  const int start = blockIdx.x * EPB;
  const int end = start + EPB < N_EDGES ? start + EPB : N_EDGES;
  for (int i = tid; i < NBUK; i += 256) h[i] = 0;
  __syncthreads();
  for (int e = start + tid; e < end; e += 256)
    atomicAdd(&h[edst[e] >> 7], 1);
  __syncthreads();
  for (int i = tid; i < NBUK; i += 256) {
    int c = h[i];
    gb[i] = c ? atomicAdd(&cursorp[i << 4], c) : 0;
    h[i] = 0;
  }
  __syncthreads();
  for (int e = start + tid; e < end; e += 256) {
    int d = edst[e];  // L2-hot (chunk re-read)
    int b = d >> 7;
    int r = atomicAdd(&h[b], 1);
    tmp[gb[b] + r] =
        make_int2(esrc[e] | ((d & 127) << 17), __float_as_int(eval[e]));
  }
}

__global__ __launch_bounds__(256) void sort_bucket_kernel(
    const int* __restrict__ base, const int2* __restrict__ tmp,
    int2* __restrict__ csr, int* __restrict__ rowptr) {
  __shared__ int2 ebuf[BCAP];
  __shared__ int bin[128], sc[128], cur[128];
  const int b = blockIdx.x, tid = threadIdx.x;
  const int bbase = base[b], bend = base[b + 1];
  const int bcnt = bend - bbase;
  if (tid < 128) bin[tid] = 0;
  __syncthreads();
  for (int i = tid; i < bcnt; i += 256) {
    int2 e = tmp[bbase + i];
    if (i < BCAP) ebuf[i] = e;
    atomicAdd(&bin[(e.x >> 17) & 127], 1);
  }
  __syncthreads();
  if (tid < 128) sc[tid] = bin[tid];
  __syncthreads();
  #pragma unroll
  for (int off = 1; off < 128; off <<= 1) {
    int u = (tid < 128 && tid >= off) ? sc[tid - off] : 0;
    __syncthreads();
    if (tid < 128) sc[tid] += u;
    __syncthreads();
  }
  if (tid < 128) {
    int ex = sc[tid] - bin[tid];
    int node = (b << 7) + tid;
    if (node < N_NODES) rowptr[node] = bbase + ex;
    cur[tid] = ex;
  }
  __syncthreads();
  for (int i = tid; i < bcnt; i += 256) {
    int2 e = (i < BCAP) ? ebuf[i] : tmp[bbase + i];
    int d = (e.x >> 17) & 127;
    int p = atomicAdd(&cur[d], 1);
    csr[bbase + p] = make_int2(e.x & 0x1FFFF, e.y);
  }
}

// ---------------------------------------------------------------------------
// W transpose + fp32->bf16: Wt[n*K + k] = bf16(W[k*N + n]). K = 1<<ksh.
// ---------------------------------------------------------------------------
__global__ __launch_bounds__(256) void transpose_w_kernel(
    const float* __restrict__ W, unsigned short* __restrict__ Wt,
    int ksh, int N) {
  int idx = blockIdx.x * 256 + threadIdx.x;
  int K = 1 << ksh;
  if (idx >= N * K) return;
  int n = idx >> ksh;
  int k = idx & (K - 1);
  Wt[idx] = (unsigned short)f_to_bf1(W[(size_t)k * N + n]);
}

// ---------------------------------------------------------------------------
// MFMA bf16 GEMM: out[M x N] = act(X)[M x K] @ W[K x N] + bias
// Wt is W^T in bf16 (n-major, k-contiguous). BM=BN=128, BK=32.
// OF8: output fp8 e4m3 (ldo in BYTES); else bf16 (ldo in elements).
// R5->R6: reg-staged double-buffered pipeline. Old loop had 2 barriers/step
// and a vmcnt(0) drain exposing full load latency every step (MfmaUtil 5.6%,
// all pipes idle, 180 us). Now: issue next tile -> regs, MFMA current buf,
// write regs -> other buf, ONE barrier. Latency hides under MFMA phase.
// ---------------------------------------------------------------------------
#define GEMM_ISSUE(k0)                                                      \
  if (AFP32) {                                                              \
    const float* X = (const float*)Xv;                                      \
    _Pragma("unroll") for (int i = 0; i < 4; ++i) {                         \
      int c = tid + i * 256;                                                \
      int row = c >> 3, kc = (c & 7) * 4;                                   \
      fa[i] = make_float4(0.f, 0.f, 0.f, 0.f);                              \
      if (bm + row < M)                                                     \
        fa[i] = *(const float4*)(X + (size_t)(bm + row) * K + (k0) + kc);   \
    }                                                                       \
  } else {                                                                  \
    const unsigned short* X = (const unsigned short*)Xv;                    \
    _Pragma("unroll") for (int i = 0; i < 2; ++i) {                         \
      int c = tid + i * 256;                                                \
      int row = c >> 2, kc = (c & 3) * 8;                                   \
      va[i] = make_uint4(0u, 0u, 0u, 0u);                                   \
      if (bm + row < M)                                                     \
        va[i] = *(const uint4*)(X + (size_t)(bm + row) * K + (k0) + kc);    \
    }                                                                       \
  }                                                                         \
  {                                                                         \
    _Pragma("unroll") for (int i = 0; i < 2; ++i) {                         \
      int c = tid + i * 256;                                                \
      int row = c >> 2, kc = (c & 3) * 8;                                   \
      vb[i] = make_uint4(0u, 0u, 0u, 0u);                                   \
      if (bn + row < N)                                                     \
        vb[i] = *(const uint4*)(Wt + (size_t)(bn + row) * K + (k0) + kc);   \
    }                                                                       \
  }

#define GEMM_WRITE(buf)                                                     \
  if (AFP32) {                                                              \
    _Pragma("unroll") for (int i = 0; i < 4; ++i) {                         \
      int c = tid + i * 256;                                                \
      int row = c >> 3, kc = (c & 7) * 4;                                   \
      unsigned lo = f2_to_bf2(fa[i].x, fa[i].y);                            \
      unsigned hi = f2_to_bf2(fa[i].z, fa[i].w);                            \
      *(uint2*)&a_lds[buf][row * LDSTR + kc] = make_uint2(lo, hi);          \
    }                                                                       \
  } else {                                                                  \
    _Pragma("unroll") for (int i = 0; i < 2; ++i) {                         \
      int c = tid + i * 256;                                                \
      int row = c >> 2, kc = (c & 3) * 8;                                   \
      uint4 v = va[i];                                                      \
      if (RELU) {                                                           \
        v.x = relu_bf2(v.x); v.y = relu_bf2(v.y);                           \
        v.z = relu_bf2(v.z); v.w = relu_bf2(v.w);                           \
      }                                                                     \
      *(uint4*)&a_lds[buf][row * LDSTR + kc] = v;                           \
    }                                                                       \
  }                                                                         \
  {                                                                         \
    _Pragma("unroll") for (int i = 0; i < 2; ++i) {                         \
      int c = tid + i * 256;                                                \
      int row = c >> 2, kc = (c & 3) * 8;                                   \
      *(uint4*)&b_lds[buf][row * LDSTR + kc] = vb[i];                       \
    }                                                                       \
  }

template<bool AFP32, bool RELU, bool OF8>
__global__ __launch_bounds__(256) void mfma_gemm_kernel(
    const void* __restrict__ Xv, const unsigned short* __restrict__ Wt,
    const float* __restrict__ bias, void* __restrict__ out,
    int M, int K, int N, int ldo) {
  constexpr int BM = 128, BN = 128, BK = 32, LDSTR = 40;
  __shared__ __align__(16) unsigned short a_lds[2][BM * LDSTR];
  __shared__ __align__(16) unsigned short b_lds[2][BN * LDSTR];

  const int tid = threadIdx.x;
  const int lane = tid & 63;
  const int wave = tid >> 6;
  const int q = lane >> 4;
  const int r16 = lane & 15;
  const int wm = (wave >> 1) * 64;
  const int wn = (wave & 1) * 64;
  const int bm = blockIdx.x * BM;
  const int bn = blockIdx.y * BN;

  floatx4 acc[4][4] = {};
  float4 fa[4];  // AFP32 staging regs
  uint4 va[2];   // bf16 A staging regs
  uint4 vb[2];   // B staging regs

  // prologue: stage tile 0
  GEMM_ISSUE(0);
  GEMM_WRITE(0);
  __syncthreads();

  int cur = 0;
  for (int k0 = 0; k0 < K; k0 += BK) {
    const bool more = (k0 + BK) < K;
    if (more) { GEMM_ISSUE(k0 + BK); }  // prefetch next tile -> regs

    bf16x8 af[4], bfr[4];
    #pragma unroll
    for (int t = 0; t < 4; ++t)
      af[t] = *(const bf16x8*)&a_lds[cur][(wm + t * 16 + r16) * LDSTR + q * 8];
    #pragma unroll
    for (int t = 0; t < 4; ++t)
      bfr[t] = *(const bf16x8*)&b_lds[cur][(wn + t * 16 + r16) * LDSTR + q * 8];
    #pragma unroll
    for (int mi = 0; mi < 4; ++mi)
      #pragma unroll
      for (int ni = 0; ni < 4; ++ni)
        acc[mi][ni] = __builtin_amdgcn_mfma_f32_16x16x32_bf16(
            af[mi], bfr[ni], acc[mi][ni], 0, 0, 0);

    if (more) {
      GEMM_WRITE(cur ^ 1);  // vmcnt wait lands here, after MFMA phase
      __syncthreads();      // single barrier per K-step
      cur ^= 1;
    }
  }

  #pragma unroll
  for (int ni = 0; ni < 4; ++ni) {
    int col = bn + wn + ni * 16 + r16;
    float bv = (col < N) ? bias[col] : 0.f;
    #pragma unroll
    for (int mi = 0; mi < 4; ++mi) {
      #pragma unroll
      for (int r = 0; r < 4; ++r) {
        int row = bm + wm + mi * 16 + q * 4 + r;
        float v = acc[mi][ni][r] + bv;
        if (OF8) {
          // 4 lanes (consecutive cols) combine into one 4 B fp8 store.
          float vo = __shfl_xor(v, 1);
          int pk = __builtin_amdgcn_cvt_pk_fp8_f32(v, vo, 0, false);
          int pk2 = __shfl_xor(pk, 2);
          unsigned four = ((unsigned)pk & 0xFFFFu) | ((unsigned)pk2 << 16);
          if (((lane & 3) == 0) && row < M && col < N) {
            *(unsigned*)((unsigned char*)out + (size_t)row * ldo + col) = four;
          }
        } else {
          int bits = (int)f_to_bf1(v);
          int other = __shfl_xor(bits, 1);
          if (((lane & 1) == 0) && row < M && col < N) {
            *(unsigned*)((unsigned short*)out + (size_t)row * ldo + col) =
                (unsigned)bits | ((unsigned)other << 16);
          }
        }
      }
    }
  }
}

// ---------------------------------------------------------------------------
// Node-parallel SpMM over fp8 activations, no atomics, x4 MLP unroll.
// Layer 0: s rows = 256 fp8 (256 B); lane holds features 4*lane..4*lane+3.
// Output h bf16 row-major 256 (matches GEMM-L1 A layout).
// ---------------------------------------------------------------------------
__global__ __launch_bounds__(256) void spmm256f8_kernel(
    const int* __restrict__ rowptr, const int2* __restrict__ csr,
    const unsigned char* __restrict__ s, bf16_t* __restrict__ h) {
  int node = blockIdx.x * 4 + (threadIdx.x >> 6);
  int lane = threadIdx.x & 63;
  if (node >= N_NODES) return;
  int beg = rowptr[node], end = rowptr[node + 1];
  float4 a0 = make_float4(0.f, 0.f, 0.f, 0.f);
  float4 a1 = a0, a2 = a0, a3 = a0;
  int i = beg;
  for (; i + 4 <= end; i += 4) {
    int2 e0 = csr[i + 0], e1 = csr[i + 1], e2 = csr[i + 2], e3 = csr[i + 3];
    unsigned r0 = *((const unsigned*)(s + (size_t)e0.x * 256) + lane);
    unsigned r1 = *((const unsigned*)(s + (size_t)e1.x * 256) + lane);
    unsigned r2 = *((const unsigned*)(s + (size_t)e2.x * 256) + lane);
    unsigned r3 = *((const unsigned*)(s + (size_t)e3.x * 256) + lane);
    float v0 = __int_as_float(e0.y);
    f32x2 l0 = __builtin_amdgcn_cvt_pk_f32_fp8((int)r0, false);
    f32x2 h0 = __builtin_amdgcn_cvt_pk_f32_fp8((int)r0, true);
    a0.x += v0 * l0[0]; a0.y += v0 * l0[1];
    a0.z += v0 * h0[0]; a0.w += v0 * h0[1];
    float v1 = __int_as_float(e1.y);
    f32x2 l1 = __builtin_amdgcn_cvt_pk_f32_fp8((int)r1, false);
    f32x2 h1 = __builtin_amdgcn_cvt_pk_f32_fp8((int)r1, true);
    a1.x += v1 * l1[0]; a1.y += v1 * l1[1];
    a1.z += v1 * h1[0]; a1.w += v1 * h1[1];
    float v2 = __int_as_float(e2.y);
    f32x2 l2 = __builtin_amdgcn_cvt_pk_f32_fp8((int)r2, false);
    f32x2 h2 = __builtin_amdgcn_cvt_pk_f32_fp8((int)r2, true);
    a2.x += v2 * l2[0]; a2.y += v2 * l2[1];
    a2.z += v2 * h2[0]; a2.w += v2 * h2[1];
    float v3 = __int_as_float(e3.y);
    f32x2 l3 = __builtin_amdgcn_cvt_pk_f32_fp8((int)r3, false);
    f32x2 h3 = __builtin_amdgcn_cvt_pk_f32_fp8((int)r3, true);
    a3.x += v3 * l3[0]; a3.y += v3 * l3[1];
    a3.z += v3 * h3[0]; a3.w += v3 * h3[1];
  }
  for (; i < end; ++i) {
    int2 e = csr[i];
    unsigned r = *((const unsigned*)(s + (size_t)e.x * 256) + lane);
    float v = __int_as_float(e.y);
    f32x2 lo = __builtin_amdgcn_cvt_pk_f32_fp8((int)r, false);
    f32x2 hi = __builtin_amdgcn_cvt_pk_f32_fp8((int)r, true);
    a0.x += v * lo[0]; a0.y += v * lo[1];
    a0.z += v * hi[0]; a0.w += v * hi[1];
  }
  float4 acc;
  acc.x = (a0.x + a1.x) + (a2.x + a3.x);
  acc.y = (a0.y + a1.y) + (a2.y + a3.y);
  acc.z = (a0.z + a1.z) + (a2.z + a3.z);
  acc.w = (a0.w + a1.w) + (a2.w + a3.w);
  uint2 o = make_uint2(f2_to_bf2(acc.x, acc.y), f2_to_bf2(acc.z, acc.w));
  *((uint2*)(h + (size_t)node * 256) + lane) = o;
}

// Layer 1: s rows = 128 fp8 (128 B); 2 nodes per wave, 32 lanes each.
__global__ __launch_bounds__(256) void spmm128f8_kernel(
    const int* __restrict__ rowptr, const int2* __restrict__ csr,
    const unsigned char* __restrict__ s, bf16_t* __restrict__ h) {
  int node = blockIdx.x * 8 + (threadIdx.x >> 5);
  int l = threadIdx.x & 31;
  if (node >= N_NODES) return;
  int beg = rowptr[node], end = rowptr[node + 1];
  float4 a0 = make_float4(0.f, 0.f, 0.f, 0.f);
  float4 a1 = a0, a2 = a0, a3 = a0;
  int i = beg;
  for (; i + 4 <= end; i += 4) {
    int2 e0 = csr[i + 0], e1 = csr[i + 1], e2 = csr[i + 2], e3 = csr[i + 3];
    unsigned r0 = *((const unsigned*)(s + (size_t)e0.x * 128) + l);
    unsigned r1 = *((const unsigned*)(s + (size_t)e1.x * 128) + l);
    unsigned r2 = *((const unsigned*)(s + (size_t)e2.x * 128) + l);
    unsigned r3 = *((const unsigned*)(s + (size_t)e3.x * 128) + l);
    float v0 = __int_as_float(e0.y);
    f32x2 l0 = __builtin_amdgcn_cvt_pk_f32_fp8((int)r0, false);
    f32x2 h0 = __builtin_amdgcn_cvt_pk_f32_fp8((int)r0, true);
    a0.x += v0 * l0[0]; a0.y += v0 * l0[1];
    a0.z += v0 * h0[0]; a0.w += v0 * h0[1];
    float v1 = __int_as_float(e1.y);
    f32x2 l1 = __builtin_amdgcn_cvt_pk_f32_fp8((int)r1, false);
    f32x2 h1 = __builtin_amdgcn_cvt_pk_f32_fp8((int)r1, true);
    a1.x += v1 * l1[0]; a1.y += v1 * l1[1];
    a1.z += v1 * h1[0]; a1.w += v1 * h1[1];
    float v2 = __int_as_float(e2.y);
    f32x2 l2 = __builtin_amdgcn_cvt_pk_f32_fp8((int)r2, false);
    f32x2 h2 = __builtin_amdgcn_cvt_pk_f32_fp8((int)r2, true);
    a2.x += v2 * l2[0]; a2.y += v2 * l2[1];
    a2.z += v2 * h2[0]; a2.w += v2 * h2[1];
    float v3 = __int_as_float(e3.y);
    f32x2 l3 = __builtin_amdgcn_cvt_pk_f32_fp8((int)r3, false);
    f32x2 h3 = __builtin_amdgcn_cvt_pk_f32_fp8((int)r3, true);
    a3.x += v3 * l3[0]; a3.y += v3 * l3[1];
    a3.z += v3 * h3[0]; a3.w += v3 * h3[1];
  }
  for (; i < end; ++i) {
    int2 e = csr[i];
    unsigned r = *((const unsigned*)(s + (size_t)e.x * 128) + l);
    float v = __int_as_float(e.y);
    f32x2 lo = __builtin_amdgcn_cvt_pk_f32_fp8((int)r, false);
    f32x2 hi = __builtin_amdgcn_cvt_pk_f32_fp8((int)r, true);
    a0.x += v * lo[0]; a0.y += v * lo[1];
    a0.z += v * hi[0]; a0.w += v * hi[1];
  }
  float4 acc;
  acc.x = (a0.x + a1.x) + (a2.x + a3.x);
  acc.y = (a0.y + a1.y) + (a2.y + a3.y);
  acc.z = (a0.z + a1.z) + (a2.z + a3.z);
  acc.w = (a0.w + a1.w) + (a2.w + a3.w);
  uint2 o = make_uint2(f2_to_bf2(acc.x, acc.y), f2_to_bf2(acc.z, acc.w));
  *((uint2*)(h + (size_t)node * 128) + l) = o;
}

// Layer 2 (kept bf16 for accuracy): s row stride 64 bf16 (128 B).
__global__ __launch_bounds__(256) void spmm40_kernel(
    const int* __restrict__ rowptr, const int2* __restrict__ csr,
    const bf16_t* __restrict__ s, float* __restrict__ out) {
  int node = blockIdx.x * 8 + (threadIdx.x >> 5);
  int l = threadIdx.x & 31;
  if (node >= N_NODES) return;
  bool active = (l < 20);
  int beg = rowptr[node], end = rowptr[node + 1];
  float2 a0 = make_float2(0.f, 0.f), a1 = a0, a2 = a0, a3 = a0;
  int i = beg;
  for (; i + 4 <= end; i += 4) {
    int2 e0 = csr[i + 0], e1 = csr[i + 1], e2 = csr[i + 2], e3 = csr[i + 3];
    unsigned r0 = active ? *((const unsigned*)(s + (size_t)e0.x * 64) + l) : 0u;
    unsigned r1 = active ? *((const unsigned*)(s + (size_t)e1.x * 64) + l) : 0u;
    unsigned r2 = active ? *((const unsigned*)(s + (size_t)e2.x * 64) + l) : 0u;
    unsigned r3 = active ? *((const unsigned*)(s + (size_t)e3.x * 64) + l) : 0u;
    float v0 = __int_as_float(e0.y);
    float2 f0 = bf2_to_f2(r0);
    a0.x += v0 * f0.x; a0.y += v0 * f0.y;
    float v1 = __int_as_float(e1.y);
    float2 f1 = bf2_to_f2(r1);
    a1.x += v1 * f1.x; a1.y += v1 * f1.y;
    float v2 = __int_as_float(e2.y);
    float2 f2 = bf2_to_f2(r2);
    a2.x += v2 * f2.x; a2.y += v2 * f2.y;
    float v3 = __int_as_float(e3.y);
    float2 f3 = bf2_to_f2(r3);
    a3.x += v3 * f3.x; a3.y += v3 * f3.y;
  }
  for (; i < end; ++i) {
    int2 e = csr[i];
    unsigned r = active ? *((const unsigned*)(s + (size_t)e.x * 64) + l) : 0u;
    float v = __int_as_float(e.y);
    float2 f = bf2_to_f2(r);
    a0.x += v * f.x; a0.y += v * f.y;
  }
  float2 acc;
  acc.x = (a0.x + a1.x) + (a2.x + a3.x);
  acc.y = (a0.y + a1.y) + (a2.y + a3.y);
  if (active) *((float2*)(out + (size_t)node * 40) + l) = acc;
}

// ---------------------------------------------------------------------------
// log_softmax over 40 classes; one wave per row, in-place fp32.
// ---------------------------------------------------------------------------
__global__ __launch_bounds__(256) void logsoftmax_kernel(float* __restrict__ io,
                                                         int M) {
  const int lane = threadIdx.x & 63;
  const int row = blockIdx.x * 4 + (threadIdx.x >> 6);
  if (row >= M) return;
  float v = (lane < 40) ? io[(size_t)row * 40 + lane] : -INFINITY;
  float m = v;
  #pragma unroll
  for (int off = 32; off > 0; off >>= 1)
    m = fmaxf(m, __shfl_xor(m, off));
  float ex = (lane < 40) ? __expf(v - m) : 0.f;
  float sum = ex;
  #pragma unroll
  for (int off = 32; off > 0; off >>= 1)
    sum += __shfl_xor(sum, off);
  if (lane < 40) io[(size_t)row * 40 + lane] = v - m - logf(sum);
}

// ---------------------------------------------------------------------------
extern "C" void kernel_launch(void* const* d_in, const int* in_sizes, int n_in,
                              void* d_out, int out_size, void* d_ws,
                              size_t ws_size, hipStream_t stream) {
  const float* x    = (const float*)d_in[0];
  const int*   esrc = (const int*)d_in[1];
  const int*   edst = (const int*)d_in[2];
  const float* eval = (const float*)d_in[3];
  const float* W0   = (const float*)d_in[4];
  const float* b0   = (const float*)d_in[5];
  const float* W1   = (const float*)d_in[6];
  const float* b1   = (const float*)d_in[7];
  const float* W2   = (const float*)d_in[8];
  const float* b2   = (const float*)d_in[9];
  float* out = (float*)d_out;

  char* ws = (char*)d_ws;
  unsigned char* bufA = (unsigned char*)(ws + 0);  // s buffers (fp8/bf16)
  bf16_t* bufB    = (bf16_t*)(ws + 51200000);     // h buffers (bf16)
  int2*   csr     = (int2*)  (ws + 102400000);    // 25.6 MB
  int2*   tmp     = (int2*)  (ws + 128000000);    // 25.6 MB
  int*    rowptr  = (int*)   (ws + 153600000);    // 400,004 B
  int*    cntp    = (int*)   (ws + 154004480);    // 50,048 B (padded)
  int*    cursorp = (int*)   (ws + 154058752);    // 50,048 B (padded)
  int*    base    = (int*)   (ws + 154112000);    // 3,132 B
  unsigned short* Wt0 = (unsigned short*)(ws + 154120192);  // 262,144 B
  unsigned short* Wt1 = (unsigned short*)(ws + 154390528);  //  65,536 B
  unsigned short* Wt2 = (unsigned short*)(ws + 154460160);  //  10,240 B

  const int M = N_NODES;
  dim3 blk(256);

  // ---- CSR build: bucketed two-pass sort, block-staged scatter ----
  hipMemsetAsync(cntp, 0, NBUK * 64, stream);
  bucket_hist_kernel<<<NBUK, blk, 0, stream>>>(edst, cntp);
  scan_buckets_kernel<<<1, 1024, 0, stream>>>(cntp, base, cursorp, rowptr);
  staged_scatter_kernel<<<(N_EDGES + EPB - 1) / EPB, blk, 0, stream>>>(
      esrc, edst, eval, cursorp, tmp);
  sort_bucket_kernel<<<NBUK, blk, 0, stream>>>(base, tmp, csr, rowptr);

  // ---- W transposes (fp32 -> bf16, n-major) ----
  transpose_w_kernel<<<(512 * 256 + 255) / 256, blk, 0, stream>>>(W0, Wt0, 9, 256);
  transpose_w_kernel<<<(256 * 128 + 255) / 256, blk, 0, stream>>>(W1, Wt1, 8, 128);
  transpose_w_kernel<<<(128 * 40 + 255) / 256, blk, 0, stream>>>(W2, Wt2, 7, 40);

  const int MB = (M + 127) / 128;  // 782

  // ---- Layer 0: s0 = x @ W0 + b0  [100000 x 256] fp8, ldo = 256 B ----
  mfma_gemm_kernel<true, false, true><<<dim3(MB, 2), blk, 0, stream>>>(
      x, Wt0, b0, bufA, M, 512, 256, 256);
  spmm256f8_kernel<<<25000, blk, 0, stream>>>(rowptr, csr, bufA, bufB);

  // ---- Layer 1: s1 = relu(h1) @ W1 + b1  [100000 x 128] fp8, ldo = 128 B ----
  mfma_gemm_kernel<false, true, true><<<dim3(MB, 1), blk, 0, stream>>>(
      bufB, Wt1, b1, bufA, M, 256, 128, 128);
  spmm128f8_kernel<<<12500, blk, 0, stream>>>(rowptr, csr, bufA, bufB);

  // ---- Layer 2: s2 = relu(h2) @ W2 + b2  [100000 x 40] bf16, stride 64 ----
  mfma_gemm_kernel<false, true, false><<<dim3(MB, 1), blk, 0, stream>>>(
      bufB, Wt2, b2, bufA, M, 128, 40, 64);
  spmm40_kernel<<<12500, blk, 0, stream>>>(rowptr, csr, (const bf16_t*)bufA, out);

  // ---- log_softmax in-place on d_out ----
  logsoftmax_kernel<<<25000, blk, 0, stream>>>(out, M);
}

// Round 7
// 914.566 us; speedup vs baseline: 1.0835x; 1.0835x over previous
//
#include <hip/hip_runtime.h>
#include <hip/hip_bf16.h>
#include <math.h>

#define N_NODES 100000
#define N_EDGES 3200000
#define NBUK 782      // ceil(100000 / 128), bucket = dst >> 7
#define BCAP 4800     // per-bucket LDS capacity (mean 4096, sigma ~64)
#define EPB 12500     // edges per staged-scatter block (256 blocks exactly)

typedef __hip_bfloat16 bf16_t;
typedef __attribute__((ext_vector_type(8))) short bf16x8;
typedef __attribute__((ext_vector_type(4))) float floatx4;
typedef __attribute__((ext_vector_type(2))) float f32x2;

// ---------- bf16 helpers (manual, branch-free) ----------
__device__ inline float2 bf2_to_f2(unsigned u) {
  float2 f;
  f.x = __uint_as_float(u << 16);
  f.y = __uint_as_float(u & 0xffff0000u);
  return f;
}
__device__ inline unsigned f2_to_bf2(float x, float y) {
  unsigned ux = __float_as_uint(x);
  unsigned uy = __float_as_uint(y);
  unsigned bx = (ux + 0x7fffu + ((ux >> 16) & 1u)) >> 16;
  unsigned by = (uy + 0x7fffu + ((uy >> 16) & 1u)) & 0xffff0000u;
  return bx | by;
}
__device__ inline unsigned f_to_bf1(float x) {
  unsigned u = __float_as_uint(x);
  return (u + 0x7fffu + ((u >> 16) & 1u)) >> 16;
}
__device__ inline unsigned relu_bf2(unsigned u) {
  unsigned lo = (u & 0x8000u) ? 0u : (u & 0xFFFFu);
  unsigned hi = (u & 0x80000000u) ? 0u : (u & 0xFFFF0000u);
  return lo | hi;
}
__device__ inline bf16x8 u4_to_bf8(uint4 v) {
  union { uint4 u; bf16x8 b; } c;
  c.u = v;
  return c.b;
}

// Async global->LDS, 16 B per lane. Dest is wave-uniform base + lane*16
// (linear; no padding allowed). Source address is per-lane.
#define GLOAD16(gp, lp)                                                        \
  __builtin_amdgcn_global_load_lds(                                            \
      (const __attribute__((address_space(1))) unsigned int*)(const void*)(gp),\
      (__attribute__((address_space(3))) unsigned int*)(void*)(lp), 16, 0, 0)

// ---------------------------------------------------------------------------
// CSR build, bucketed two-pass with block-staged scatter (R4: WRITE_SIZE
// 180 MB -> full-line writebacks; scatter off the critical top-5).
// ---------------------------------------------------------------------------
__global__ __launch_bounds__(256) void bucket_hist_kernel(
    const int* __restrict__ edst, int* __restrict__ cntp) {
  __shared__ int h[NBUK];
  for (int i = threadIdx.x; i < NBUK; i += 256) h[i] = 0;
  __syncthreads();
  int start = blockIdx.x * 4096;
  int end = start + 4096 < N_EDGES ? start + 4096 : N_EDGES;
  for (int i = start + threadIdx.x; i < end; i += 256)
    atomicAdd(&h[edst[i] >> 7], 1);
  __syncthreads();
  for (int i = threadIdx.x; i < NBUK; i += 256)
    if (h[i]) atomicAdd(&cntp[i << 4], h[i]);
}

__global__ __launch_bounds__(1024) void scan_buckets_kernel(
    const int* __restrict__ cntp, int* __restrict__ base,
    int* __restrict__ cursorp, int* __restrict__ rowptr) {
  __shared__ int sc[1024];
  int t = threadIdx.x;
  int v = (t < NBUK) ? cntp[t << 4] : 0;
  sc[t] = v;
  __syncthreads();
  #pragma unroll
  for (int off = 1; off < 1024; off <<= 1) {
    int u = (t >= off) ? sc[t - off] : 0;
    __syncthreads();
    sc[t] += u;
    __syncthreads();
  }
  int ex = sc[t] - v;  // exclusive
  if (t < NBUK) { base[t] = ex; cursorp[t << 4] = ex; }
  if (t == NBUK - 1) base[NBUK] = ex + v;
  if (t == 0) rowptr[N_NODES] = N_EDGES;
}

__global__ __launch_bounds__(256) void staged_scatter_kernel(
    const int* __restrict__ esrc, const int* __restrict__ edst,
    const float* __restrict__ eval, int* __restrict__ cursorp,
    int2* __restrict__ tmp) {
  __shared__ int h[NBUK];   // local hist, then local cursor
  __shared__ int gb[NBUK];  // reserved global base per bucket
  const int tid = threadIdx.x;
  const int start = blockIdx.x * EPB;
  const int end = start + EPB < N_EDGES ? start + EPB : N_EDGES;
  for (int i = tid; i < NBUK; i += 256) h[i] = 0;
  __syncthreads();
  for (int e = start + tid; e < end; e += 256)
    atomicAdd(&h[edst[e] >> 7], 1);
  __syncthreads();
  for (int i = tid; i < NBUK; i += 256) {
    int c = h[i];
    gb[i] = c ? atomicAdd(&cursorp[i << 4], c) : 0;
    h[i] = 0;
  }
  __syncthreads();
  for (int e = start + tid; e < end; e += 256) {
    int d = edst[e];  // L2-hot (chunk re-read)
    int b = d >> 7;
    int r = atomicAdd(&h[b], 1);
    tmp[gb[b] + r] =
        make_int2(esrc[e] | ((d & 127) << 17), __float_as_int(eval[e]));
  }
}

__global__ __launch_bounds__(256) void sort_bucket_kernel(
    const int* __restrict__ base, const int2* __restrict__ tmp,
    int2* __restrict__ csr, int* __restrict__ rowptr) {
  __shared__ int2 ebuf[BCAP];
  __shared__ int bin[128], sc[128], cur[128];
  const int b = blockIdx.x, tid = threadIdx.x;
  const int bbase = base[b], bend = base[b + 1];
  const int bcnt = bend - bbase;
  if (tid < 128) bin[tid] = 0;
  __syncthreads();
  for (int i = tid; i < bcnt; i += 256) {
    int2 e = tmp[bbase + i];
    if (i < BCAP) ebuf[i] = e;
    atomicAdd(&bin[(e.x >> 17) & 127], 1);
  }
  __syncthreads();
  if (tid < 128) sc[tid] = bin[tid];
  __syncthreads();
  #pragma unroll
  for (int off = 1; off < 128; off <<= 1) {
    int u = (tid < 128 && tid >= off) ? sc[tid - off] : 0;
    __syncthreads();
    if (tid < 128) sc[tid] += u;
    __syncthreads();
  }
  if (tid < 128) {
    int ex = sc[tid] - bin[tid];
    int node = (b << 7) + tid;
    if (node < N_NODES) rowptr[node] = bbase + ex;
    cur[tid] = ex;
  }
  __syncthreads();
  for (int i = tid; i < bcnt; i += 256) {
    int2 e = (i < BCAP) ? ebuf[i] : tmp[bbase + i];
    int d = (e.x >> 17) & 127;
    int p = atomicAdd(&cur[d], 1);
    csr[bbase + p] = make_int2(e.x & 0x1FFFF, e.y);
  }
}

// ---------------------------------------------------------------------------
// W transpose + fp32->bf16: Wt[n*K + k] = bf16(W[k*N + n]). K = 1<<ksh.
// ---------------------------------------------------------------------------
__global__ __launch_bounds__(256) void transpose_w_kernel(
    const float* __restrict__ W, unsigned short* __restrict__ Wt,
    int ksh, int N) {
  int idx = blockIdx.x * 256 + threadIdx.x;
  int K = 1 << ksh;
  if (idx >= N * K) return;
  int n = idx >> ksh;
  int k = idx & (K - 1);
  Wt[idx] = (unsigned short)f_to_bf1(W[(size_t)k * N + n]);
}

// ---------------------------------------------------------------------------
// MFMA bf16 GEMM: out[M x N] = act(X)[M x K] @ W[K x N] + bias
// R6->R7: m97 structure — global_load_lds (width 16) direct staging into
// double-buffered LINEAR LDS, one barrier per K-step. Reg-staged version
// (R6) exposed full load latency after the short MFMA phase and cut
// occupancy (232 us, MfmaUtil 4.5%). Bank conflicts handled by XOR chunk
// swizzle applied to BOTH global source and LDS read address (rule #21:
// same involution both sides, dest stays linear). fp32 A (L0) is staged
// raw and converted at fragment-read; ReLU applied at fragment-read.
// OF8: output fp8 e4m3 (ldo in BYTES); else bf16 (ldo in elements).
// ---------------------------------------------------------------------------
template<bool AFP32, bool RELU, bool OF8>
__global__ __launch_bounds__(256) void mfma_gemm_kernel(
    const void* __restrict__ Xv, const unsigned short* __restrict__ Wt,
    const float* __restrict__ bias, void* __restrict__ out,
    int M, int K, int N, int ldo) {
  constexpr int BM = 128, BN = 128, BK = 32;
  constexpr int ABUF = BM * BK * (AFP32 ? 4 : 2);  // bytes per A buffer
  constexpr int BBUF = BN * BK * 2;                // bytes per B buffer
  __shared__ __align__(16) char lds[2 * ABUF + 2 * BBUF];
  char* const a0 = lds;
  char* const b0 = lds + 2 * ABUF;

  const int tid = threadIdx.x;
  const int lane = tid & 63;
  const int wave = tid >> 6;
  const int q = lane >> 4;
  const int r16 = lane & 15;
  const int wm = (wave >> 1) * 64;
  const int wn = (wave & 1) * 64;
  const int bm = blockIdx.x * BM;
  const int bn = blockIdx.y * BN;

  floatx4 acc[4][4] = {};

  auto stage = [&](int buf, int k0) {
    if constexpr (AFP32) {
      const float* X = (const float*)Xv;
      #pragma unroll
      for (int j = 0; j < 4; ++j) {
        int chunk = (wave * 4 + j) * 64 + lane;   // 0..1023 (16B chunks)
        int row = chunk >> 3, slot = chunk & 7;
        int g = slot ^ (row & 7);                 // src pre-swizzle
        int rowc = (bm + row < M) ? bm + row : M - 1;
        const float* gp = X + (size_t)rowc * K + k0 + g * 4;
        GLOAD16(gp, a0 + buf * ABUF + chunk * 16);
      }
    } else {
      const unsigned short* X = (const unsigned short*)Xv;
      #pragma unroll
      for (int j = 0; j < 2; ++j) {
        int chunk = (wave * 2 + j) * 64 + lane;   // 0..511
        int row = chunk >> 2, slot = chunk & 3;
        int g = slot ^ ((row >> 1) & 3);
        int rowc = (bm + row < M) ? bm + row : M - 1;
        const unsigned short* gp = X + (size_t)rowc * K + k0 + g * 8;
        GLOAD16(gp, a0 + buf * ABUF + chunk * 16);
      }
    }
    #pragma unroll
    for (int j = 0; j < 2; ++j) {
      int chunk = (wave * 2 + j) * 64 + lane;     // 0..511
      int row = chunk >> 2, slot = chunk & 3;
      int g = slot ^ ((row >> 1) & 3);
      int rowc = (bn + row < N) ? bn + row : N - 1;
      const unsigned short* gp = Wt + (size_t)rowc * K + k0 + g * 8;
      GLOAD16(gp, b0 + buf * BBUF + chunk * 16);
    }
  };

  stage(0, 0);
  __syncthreads();

  int cur = 0;
  for (int k0 = 0; k0 < K; k0 += BK) {
    if (k0 + BK < K) stage(cur ^ 1, k0 + BK);  // loads fly under this step

    bf16x8 af[4], bfr[4];
    #pragma unroll
    for (int t = 0; t < 4; ++t) {
      int row = wm + t * 16 + r16;
      if constexpr (AFP32) {
        const char* base = a0 + cur * ABUF + row * 128;
        int p = row & 7;
        float4 c0 = *(const float4*)(base + (((2 * q) ^ p) * 16));
        float4 c1 = *(const float4*)(base + (((2 * q + 1) ^ p) * 16));
        uint4 u = make_uint4(f2_to_bf2(c0.x, c0.y), f2_to_bf2(c0.z, c0.w),
                             f2_to_bf2(c1.x, c1.y), f2_to_bf2(c1.z, c1.w));
        af[t] = u4_to_bf8(u);
      } else {
        int slot = q ^ ((row >> 1) & 3);
        uint4 u = *(const uint4*)(a0 + cur * ABUF + row * 64 + slot * 16);
        if (RELU) {
          u.x = relu_bf2(u.x); u.y = relu_bf2(u.y);
          u.z = relu_bf2(u.z); u.w = relu_bf2(u.w);
        }
        af[t] = u4_to_bf8(u);
      }
    }
    #pragma unroll
    for (int t = 0; t < 4; ++t) {
      int row = wn + t * 16 + r16;
      int slot = q ^ ((row >> 1) & 3);
      uint4 u = *(const uint4*)(b0 + cur * BBUF + row * 64 + slot * 16);
      bfr[t] = u4_to_bf8(u);
    }
    #pragma unroll
    for (int mi = 0; mi < 4; ++mi)
      #pragma unroll
      for (int ni = 0; ni < 4; ++ni)
        acc[mi][ni] = __builtin_amdgcn_mfma_f32_16x16x32_bf16(
            af[mi], bfr[ni], acc[mi][ni], 0, 0, 0);

    __syncthreads();  // drains staged loads; protects cur from overwrite
    cur ^= 1;
  }

  #pragma unroll
  for (int ni = 0; ni < 4; ++ni) {
    int col = bn + wn + ni * 16 + r16;
    float bv = (col < N) ? bias[col] : 0.f;
    #pragma unroll
    for (int mi = 0; mi < 4; ++mi) {
      #pragma unroll
      for (int r = 0; r < 4; ++r) {
        int row = bm + wm + mi * 16 + q * 4 + r;
        float v = acc[mi][ni][r] + bv;
        if (OF8) {
          // 4 lanes (consecutive cols) combine into one 4 B fp8 store.
          float vo = __shfl_xor(v, 1);
          int pk = __builtin_amdgcn_cvt_pk_fp8_f32(v, vo, 0, false);
          int pk2 = __shfl_xor(pk, 2);
          unsigned four = ((unsigned)pk & 0xFFFFu) | ((unsigned)pk2 << 16);
          if (((lane & 3) == 0) && row < M && col < N) {
            *(unsigned*)((unsigned char*)out + (size_t)row * ldo + col) = four;
          }
        } else {
          int bits = (int)f_to_bf1(v);
          int other = __shfl_xor(bits, 1);
          if (((lane & 1) == 0) && row < M && col < N) {
            *(unsigned*)((unsigned short*)out + (size_t)row * ldo + col) =
                (unsigned)bits | ((unsigned)other << 16);
          }
        }
      }
    }
  }
}

// ---------------------------------------------------------------------------
// Node-parallel SpMM over fp8 activations, no atomics, x4 MLP unroll.
// Layer 0: s rows = 256 fp8 (256 B); lane holds features 4*lane..4*lane+3.
// Output h bf16 row-major 256 (matches GEMM-L1 A layout).
// ---------------------------------------------------------------------------
__global__ __launch_bounds__(256) void spmm256f8_kernel(
    const int* __restrict__ rowptr, const int2* __restrict__ csr,
    const unsigned char* __restrict__ s, bf16_t* __restrict__ h) {
  int node = blockIdx.x * 4 + (threadIdx.x >> 6);
  int lane = threadIdx.x & 63;
  if (node >= N_NODES) return;
  int beg = rowptr[node], end = rowptr[node + 1];
  float4 a0 = make_float4(0.f, 0.f, 0.f, 0.f);
  float4 a1 = a0, a2 = a0, a3 = a0;
  int i = beg;
  for (; i + 4 <= end; i += 4) {
    int2 e0 = csr[i + 0], e1 = csr[i + 1], e2 = csr[i + 2], e3 = csr[i + 3];
    unsigned r0 = *((const unsigned*)(s + (size_t)e0.x * 256) + lane);
    unsigned r1 = *((const unsigned*)(s + (size_t)e1.x * 256) + lane);
    unsigned r2 = *((const unsigned*)(s + (size_t)e2.x * 256) + lane);
    unsigned r3 = *((const unsigned*)(s + (size_t)e3.x * 256) + lane);
    float v0 = __int_as_float(e0.y);
    f32x2 l0 = __builtin_amdgcn_cvt_pk_f32_fp8((int)r0, false);
    f32x2 h0 = __builtin_amdgcn_cvt_pk_f32_fp8((int)r0, true);
    a0.x += v0 * l0[0]; a0.y += v0 * l0[1];
    a0.z += v0 * h0[0]; a0.w += v0 * h0[1];
    float v1 = __int_as_float(e1.y);
    f32x2 l1 = __builtin_amdgcn_cvt_pk_f32_fp8((int)r1, false);
    f32x2 h1 = __builtin_amdgcn_cvt_pk_f32_fp8((int)r1, true);
    a1.x += v1 * l1[0]; a1.y += v1 * l1[1];
    a1.z += v1 * h1[0]; a1.w += v1 * h1[1];
    float v2 = __int_as_float(e2.y);
    f32x2 l2 = __builtin_amdgcn_cvt_pk_f32_fp8((int)r2, false);
    f32x2 h2 = __builtin_amdgcn_cvt_pk_f32_fp8((int)r2, true);
    a2.x += v2 * l2[0]; a2.y += v2 * l2[1];
    a2.z += v2 * h2[0]; a2.w += v2 * h2[1];
    float v3 = __int_as_float(e3.y);
    f32x2 l3 = __builtin_amdgcn_cvt_pk_f32_fp8((int)r3, false);
    f32x2 h3 = __builtin_amdgcn_cvt_pk_f32_fp8((int)r3, true);
    a3.x += v3 * l3[0]; a3.y += v3 * l3[1];
    a3.z += v3 * h3[0]; a3.w += v3 * h3[1];
  }
  for (; i < end; ++i) {
    int2 e = csr[i];
    unsigned r = *((const unsigned*)(s + (size_t)e.x * 256) + lane);
    float v = __int_as_float(e.y);
    f32x2 lo = __builtin_amdgcn_cvt_pk_f32_fp8((int)r, false);
    f32x2 hi = __builtin_amdgcn_cvt_pk_f32_fp8((int)r, true);
    a0.x += v * lo[0]; a0.y += v * lo[1];
    a0.z += v * hi[0]; a0.w += v * hi[1];
  }
  float4 acc;
  acc.x = (a0.x + a1.x) + (a2.x + a3.x);
  acc.y = (a0.y + a1.y) + (a2.y + a3.y);
  acc.z = (a0.z + a1.z) + (a2.z + a3.z);
  acc.w = (a0.w + a1.w) + (a2.w + a3.w);
  uint2 o = make_uint2(f2_to_bf2(acc.x, acc.y), f2_to_bf2(acc.z, acc.w));
  *((uint2*)(h + (size_t)node * 256) + lane) = o;
}

// Layer 1: s rows = 128 fp8 (128 B); 2 nodes per wave, 32 lanes each.
__global__ __launch_bounds__(256) void spmm128f8_kernel(
    const int* __restrict__ rowptr, const int2* __restrict__ csr,
    const unsigned char* __restrict__ s, bf16_t* __restrict__ h) {
  int node = blockIdx.x * 8 + (threadIdx.x >> 5);
  int l = threadIdx.x & 31;
  if (node >= N_NODES) return;
  int beg = rowptr[node], end = rowptr[node + 1];
  float4 a0 = make_float4(0.f, 0.f, 0.f, 0.f);
  float4 a1 = a0, a2 = a0, a3 = a0;
  int i = beg;
  for (; i + 4 <= end; i += 4) {
    int2 e0 = csr[i + 0], e1 = csr[i + 1], e2 = csr[i + 2], e3 = csr[i + 3];
    unsigned r0 = *((const unsigned*)(s + (size_t)e0.x * 128) + l);
    unsigned r1 = *((const unsigned*)(s + (size_t)e1.x * 128) + l);
    unsigned r2 = *((const unsigned*)(s + (size_t)e2.x * 128) + l);
    unsigned r3 = *((const unsigned*)(s + (size_t)e3.x * 128) + l);
    float v0 = __int_as_float(e0.y);
    f32x2 l0 = __builtin_amdgcn_cvt_pk_f32_fp8((int)r0, false);
    f32x2 h0 = __builtin_amdgcn_cvt_pk_f32_fp8((int)r0, true);
    a0.x += v0 * l0[0]; a0.y += v0 * l0[1];
    a0.z += v0 * h0[0]; a0.w += v0 * h0[1];
    float v1 = __int_as_float(e1.y);
    f32x2 l1 = __builtin_amdgcn_cvt_pk_f32_fp8((int)r1, false);
    f32x2 h1 = __builtin_amdgcn_cvt_pk_f32_fp8((int)r1, true);
    a1.x += v1 * l1[0]; a1.y += v1 * l1[1];
    a1.z += v1 * h1[0]; a1.w += v1 * h1[1];
    float v2 = __int_as_float(e2.y);
    f32x2 l2 = __builtin_amdgcn_cvt_pk_f32_fp8((int)r2, false);
    f32x2 h2 = __builtin_amdgcn_cvt_pk_f32_fp8((int)r2, true);
    a2.x += v2 * l2[0]; a2.y += v2 * l2[1];
    a2.z += v2 * h2[0]; a2.w += v2 * h2[1];
    float v3 = __int_as_float(e3.y);
    f32x2 l3 = __builtin_amdgcn_cvt_pk_f32_fp8((int)r3, false);
    f32x2 h3 = __builtin_amdgcn_cvt_pk_f32_fp8((int)r3, true);
    a3.x += v3 * l3[0]; a3.y += v3 * l3[1];
    a3.z += v3 * h3[0]; a3.w += v3 * h3[1];
  }
  for (; i < end; ++i) {
    int2 e = csr[i];
    unsigned r = *((const unsigned*)(s + (size_t)e.x * 128) + l);
    float v = __int_as_float(e.y);
    f32x2 lo = __builtin_amdgcn_cvt_pk_f32_fp8((int)r, false);
    f32x2 hi = __builtin_amdgcn_cvt_pk_f32_fp8((int)r, true);
    a0.x += v * lo[0]; a0.y += v * lo[1];
    a0.z += v * hi[0]; a0.w += v * hi[1];
  }
  float4 acc;
  acc.x = (a0.x + a1.x) + (a2.x + a3.x);
  acc.y = (a0.y + a1.y) + (a2.y + a3.y);
  acc.z = (a0.z + a1.z) + (a2.z + a3.z);
  acc.w = (a0.w + a1.w) + (a2.w + a3.w);
  uint2 o = make_uint2(f2_to_bf2(acc.x, acc.y), f2_to_bf2(acc.z, acc.w));
  *((uint2*)(h + (size_t)node * 128) + l) = o;
}

// Layer 2 (kept bf16 for accuracy): s row stride 64 bf16 (128 B).
__global__ __launch_bounds__(256) void spmm40_kernel(
    const int* __restrict__ rowptr, const int2* __restrict__ csr,
    const bf16_t* __restrict__ s, float* __restrict__ out) {
  int node = blockIdx.x * 8 + (threadIdx.x >> 5);
  int l = threadIdx.x & 31;
  if (node >= N_NODES) return;
  bool active = (l < 20);
  int beg = rowptr[node], end = rowptr[node + 1];
  float2 a0 = make_float2(0.f, 0.f), a1 = a0, a2 = a0, a3 = a0;
  int i = beg;
  for (; i + 4 <= end; i += 4) {
    int2 e0 = csr[i + 0], e1 = csr[i + 1], e2 = csr[i + 2], e3 = csr[i + 3];
    unsigned r0 = active ? *((const unsigned*)(s + (size_t)e0.x * 64) + l) : 0u;
    unsigned r1 = active ? *((const unsigned*)(s + (size_t)e1.x * 64) + l) : 0u;
    unsigned r2 = active ? *((const unsigned*)(s + (size_t)e2.x * 64) + l) : 0u;
    unsigned r3 = active ? *((const unsigned*)(s + (size_t)e3.x * 64) + l) : 0u;
    float v0 = __int_as_float(e0.y);
    float2 f0 = bf2_to_f2(r0);
    a0.x += v0 * f0.x; a0.y += v0 * f0.y;
    float v1 = __int_as_float(e1.y);
    float2 f1 = bf2_to_f2(r1);
    a1.x += v1 * f1.x; a1.y += v1 * f1.y;
    float v2 = __int_as_float(e2.y);
    float2 f2 = bf2_to_f2(r2);
    a2.x += v2 * f2.x; a2.y += v2 * f2.y;
    float v3 = __int_as_float(e3.y);
    float2 f3 = bf2_to_f2(r3);
    a3.x += v3 * f3.x; a3.y += v3 * f3.y;
  }
  for (; i < end; ++i) {
    int2 e = csr[i];
    unsigned r = active ? *((const unsigned*)(s + (size_t)e.x * 64) + l) : 0u;
    float v = __int_as_float(e.y);
    float2 f = bf2_to_f2(r);
    a0.x += v * f.x; a0.y += v * f.y;
  }
  float2 acc;
  acc.x = (a0.x + a1.x) + (a2.x + a3.x);
  acc.y = (a0.y + a1.y) + (a2.y + a3.y);
  if (active) *((float2*)(out + (size_t)node * 40) + l) = acc;
}

// ---------------------------------------------------------------------------
// log_softmax over 40 classes; one wave per row, in-place fp32.
// ---------------------------------------------------------------------------
__global__ __launch_bounds__(256) void logsoftmax_kernel(float* __restrict__ io,
                                                         int M) {
  const int lane = threadIdx.x & 63;
  const int row = blockIdx.x * 4 + (threadIdx.x >> 6);
  if (row >= M) return;
  float v = (lane < 40) ? io[(size_t)row * 40 + lane] : -INFINITY;
  float m = v;
  #pragma unroll
  for (int off = 32; off > 0; off >>= 1)
    m = fmaxf(m, __shfl_xor(m, off));
  float ex = (lane < 40) ? __expf(v - m) : 0.f;
  float sum = ex;
  #pragma unroll
  for (int off = 32; off > 0; off >>= 1)
    sum += __shfl_xor(sum, off);
  if (lane < 40) io[(size_t)row * 40 + lane] = v - m - logf(sum);
}

// ---------------------------------------------------------------------------
extern "C" void kernel_launch(void* const* d_in, const int* in_sizes, int n_in,
                              void* d_out, int out_size, void* d_ws,
                              size_t ws_size, hipStream_t stream) {
  const float* x    = (const float*)d_in[0];
  const int*   esrc = (const int*)d_in[1];
  const int*   edst = (const int*)d_in[2];
  const float* eval = (const float*)d_in[3];
  const float* W0   = (const float*)d_in[4];
  const float* b0   = (const float*)d_in[5];
  const float* W1   = (const float*)d_in[6];
  const float* b1   = (const float*)d_in[7];
  const float* W2   = (const float*)d_in[8];
  const float* b2   = (const float*)d_in[9];
  float* out = (float*)d_out;

  char* ws = (char*)d_ws;
  unsigned char* bufA = (unsigned char*)(ws + 0);  // s buffers (fp8/bf16)
  bf16_t* bufB    = (bf16_t*)(ws + 51200000);     // h buffers (bf16)
  int2*   csr     = (int2*)  (ws + 102400000);    // 25.6 MB
  int2*   tmp     = (int2*)  (ws + 128000000);    // 25.6 MB
  int*    rowptr  = (int*)   (ws + 153600000);    // 400,004 B
  int*    cntp    = (int*)   (ws + 154004480);    // 50,048 B (padded)
  int*    cursorp = (int*)   (ws + 154058752);    // 50,048 B (padded)
  int*    base    = (int*)   (ws + 154112000);    // 3,132 B
  unsigned short* Wt0 = (unsigned short*)(ws + 154120192);  // 262,144 B
  unsigned short* Wt1 = (unsigned short*)(ws + 154390528);  //  65,536 B
  unsigned short* Wt2 = (unsigned short*)(ws + 154460160);  //  10,240 B

  const int M = N_NODES;
  dim3 blk(256);

  // ---- CSR build: bucketed two-pass sort, block-staged scatter ----
  hipMemsetAsync(cntp, 0, NBUK * 64, stream);
  bucket_hist_kernel<<<NBUK, blk, 0, stream>>>(edst, cntp);
  scan_buckets_kernel<<<1, 1024, 0, stream>>>(cntp, base, cursorp, rowptr);
  staged_scatter_kernel<<<(N_EDGES + EPB - 1) / EPB, blk, 0, stream>>>(
      esrc, edst, eval, cursorp, tmp);
  sort_bucket_kernel<<<NBUK, blk, 0, stream>>>(base, tmp, csr, rowptr);

  // ---- W transposes (fp32 -> bf16, n-major) ----
  transpose_w_kernel<<<(512 * 256 + 255) / 256, blk, 0, stream>>>(W0, Wt0, 9, 256);
  transpose_w_kernel<<<(256 * 128 + 255) / 256, blk, 0, stream>>>(W1, Wt1, 8, 128);
  transpose_w_kernel<<<(128 * 40 + 255) / 256, blk, 0, stream>>>(W2, Wt2, 7, 40);

  const int MB = (M + 127) / 128;  // 782

  // ---- Layer 0: s0 = x @ W0 + b0  [100000 x 256] fp8, ldo = 256 B ----
  mfma_gemm_kernel<true, false, true><<<dim3(MB, 2), blk, 0, stream>>>(
      x, Wt0, b0, bufA, M, 512, 256, 256);
  spmm256f8_kernel<<<25000, blk, 0, stream>>>(rowptr, csr, bufA, bufB);

  // ---- Layer 1: s1 = relu(h1) @ W1 + b1  [100000 x 128] fp8, ldo = 128 B ----
  mfma_gemm_kernel<false, true, true><<<dim3(MB, 1), blk, 0, stream>>>(
      bufB, Wt1, b1, bufA, M, 256, 128, 128);
  spmm128f8_kernel<<<12500, blk, 0, stream>>>(rowptr, csr, bufA, bufB);

  // ---- Layer 2: s2 = relu(h2) @ W2 + b2  [100000 x 40] bf16, stride 64 ----
  mfma_gemm_kernel<false, true, false><<<dim3(MB, 1), blk, 0, stream>>>(
      bufB, Wt2, b2, bufA, M, 128, 40, 64);
  spmm40_kernel<<<12500, blk, 0, stream>>>(rowptr, csr, (const bf16_t*)bufA, out);

  // ---- log_softmax in-place on d_out ----
  logsoftmax_kernel<<<25000, blk, 0, stream>>>(out, M);
}